// Round 1
// baseline (13846.251 us; speedup 1.0000x reference)
//
#include <hip/hip_runtime.h>
#include <hip/hip_bf16.h>
#include <stdint.h>

// ---------------------------------------------------------------------------
// GRU over sequence. B=64, T=512, D=1024, H=1024.
//   Precompute: xproj[m][0:2048]   = x@W[:D] + W_b   (m = b*T + t)
//               xproj[m][2048:3072]= x@U[:D] + U_b
//   Sequential (persistent kernel, 2 grid barriers per step):
//     Phase A: gi = sigmoid(h_bf@Wh + gx[t]); write rh=r*h (bf16), u (fp32)
//     Phase B: c = tanh(rh@Uh + ux[t]); h = u*h + (1-u)*c; write h_fp/h_bf/out
// Recurrent weights live in VGPRs for all 512 steps (loaded once per wave).
// ---------------------------------------------------------------------------

typedef unsigned short u16;
typedef __attribute__((ext_vector_type(8))) short bf16x8;
typedef __attribute__((ext_vector_type(4))) float f32x4;

constexpr int Bsz = 64, Tt = 512, Dd = 1024, Hh = 1024;
constexpr int Mrows = Bsz * Tt;   // 32768
constexpr int NP = 3 * Hh;        // 3072
constexpr int GSEQ = 64;          // persistent blocks (<=256 CUs -> co-resident)

// workspace layout (bytes)
constexpr size_t SZ_XPROJ = (size_t)Mrows * NP * 2;   // 201326592
constexpr size_t SZ_XBF   = (size_t)Mrows * Dd * 2;   //  67108864
constexpr size_t SZ_PT    = (size_t)NP * 1024 * 2;    //   6291456
constexpr size_t SZ_WHT   = (size_t)2048 * 1024 * 2;  //   4194304
constexpr size_t SZ_UHT   = (size_t)1024 * 1024 * 2;  //   2097152
constexpr size_t OFF_XPROJ = 0;
constexpr size_t OFF_XBF   = OFF_XPROJ + SZ_XPROJ;
constexpr size_t OFF_PT    = OFF_XBF + SZ_XBF;
constexpr size_t OFF_WHT   = OFF_PT + SZ_PT;
constexpr size_t OFF_UHT   = OFF_WHT + SZ_WHT;
constexpr size_t OFF_HFP   = OFF_UHT + SZ_UHT;          // 64*1024*4
constexpr size_t OFF_HBF   = OFF_HFP + 262144;          // 64*1024*2
constexpr size_t OFF_RH    = OFF_HBF + 131072;          // 64*1024*2
constexpr size_t OFF_UFP   = OFF_RH  + 131072;          // 64*1024*4
constexpr size_t OFF_BAR   = OFF_UFP + 262144;          // 64B
constexpr size_t WS_NEEDED = OFF_BAR + 64;

__device__ __forceinline__ float b2f(u16 u) {
  union { unsigned i; float f; } x; x.i = ((unsigned)u) << 16; return x.f;
}
__device__ __forceinline__ u16 f2b(float f) {
  union { float f; unsigned i; } x; x.f = f;
  unsigned r = (x.i >> 16) & 1u;
  return (u16)((x.i + 0x7fffu + r) >> 16);
}
__device__ __forceinline__ float sigmoidf_(float x) { return 1.0f / (1.0f + __expf(-x)); }
__device__ __forceinline__ float tanhf_(float x) { return 1.0f - 2.0f / (__expf(2.0f * x) + 1.0f); }

// async global->LDS, 16B per lane; lds dest must be wave-uniform base (+lane*16 by HW)
__device__ __forceinline__ void gl2lds16(const void* g, void* l) {
  __builtin_amdgcn_global_load_lds(
      (const __attribute__((address_space(1))) void*)g,
      (__attribute__((address_space(3))) void*)l, 16, 0, 0);
}

// ------------------------------- prep kernels ------------------------------
__global__ void k_prep_x(const float* __restrict__ x, u16* __restrict__ xbf,
                         const float* __restrict__ h0, float* __restrict__ h_fp,
                         u16* __restrict__ h_bf, unsigned* __restrict__ bar) {
  size_t i = (size_t)blockIdx.x * blockDim.x + threadIdx.x;
  size_t stride = (size_t)gridDim.x * blockDim.x;
  if (i < 16) bar[i] = 0u;
  for (size_t k = i; k < (size_t)Mrows * Dd; k += stride) xbf[k] = f2b(x[k]);
  for (size_t k = i; k < (size_t)Bsz * Hh; k += stride) {
    float v = h0[k]; h_fp[k] = v; h_bf[k] = f2b(v);
  }
}

__global__ void k_prep_w(const float* __restrict__ W, const float* __restrict__ U,
                         u16* __restrict__ Pt, u16* __restrict__ Wht, u16* __restrict__ Uht) {
  size_t i = (size_t)blockIdx.x * blockDim.x + threadIdx.x;
  size_t stride = (size_t)gridDim.x * blockDim.x;
  // Pt[n][k] = (n<2048 ? W[k][n] : U[k][n-2048])   n:0..3071 k:0..1023
  for (size_t idx = i; idx < (size_t)3072 * 1024; idx += stride) {
    int n = (int)(idx >> 10), k = (int)(idx & 1023);
    float v = (n < 2048) ? W[(size_t)k * 2048 + n] : U[(size_t)k * 1024 + (n - 2048)];
    Pt[idx] = f2b(v);
  }
  // Wht[n][k] = W[1024+k][n]   n:0..2047
  for (size_t idx = i; idx < (size_t)2048 * 1024; idx += stride) {
    int n = (int)(idx >> 10), k = (int)(idx & 1023);
    Wht[idx] = f2b(W[(size_t)(1024 + k) * 2048 + n]);
  }
  // Uht[n][k] = U[1024+k][n]   n:0..1023
  for (size_t idx = i; idx < (size_t)1024 * 1024; idx += stride) {
    int n = (int)(idx >> 10), k = (int)(idx & 1023);
    Uht[idx] = f2b(U[(size_t)(1024 + k) * 1024 + n]);
  }
}

__global__ void k_ws_too_small(float* out) {
  out[threadIdx.x] = 12345.0f;  // sentinel: ws_size < WS_NEEDED
}

// --------------------------- precompute GEMM (m97) -------------------------
// C[m][n] = xbf[m][:] . Pt[n][:] + bias(n);  M=32768 N=3072 K=1024
// 128x128 tile / block(256) / 4 waves each 64x64 quadrant / BK=32
__global__ void k_gemm(const u16* __restrict__ xbf, const u16* __restrict__ Pt,
                       const float* __restrict__ Wb, const float* __restrict__ Ub,
                       u16* __restrict__ xproj) {
  __shared__ u16 As[128 * 32];
  __shared__ u16 Bs[128 * 32];
  const int tid = threadIdx.x, lane = tid & 63, w = tid >> 6;
  const int l15 = lane & 15, q = lane >> 4;
  const int bm = blockIdx.x, bn = blockIdx.y;
  const int wm = w >> 1, wn = w & 1;
  const int lr = lane >> 2;         // staging: row within 16
  const int lc = (lane & 3) * 8;    // staging: elem offset within row chunk
  f32x4 acc[4][4] = {};
  for (int kt = 0; kt < 32; ++kt) {
    __syncthreads();
    {
      const u16* ga = xbf + (size_t)(bm * 128 + w * 32 + lr) * 1024 + kt * 32 + lc;
      gl2lds16(ga, As + w * 1024);
      gl2lds16(ga + 16 * 1024, As + w * 1024 + 512);
      const u16* gb = Pt + (size_t)(bn * 128 + w * 32 + lr) * 1024 + kt * 32 + lc;
      gl2lds16(gb, Bs + w * 1024);
      gl2lds16(gb + 16 * 1024, Bs + w * 1024 + 512);
    }
    __syncthreads();
    bf16x8 af[4], bfr[4];
#pragma unroll
    for (int i = 0; i < 4; ++i)
      af[i] = *(const bf16x8*)(As + (wm * 64 + i * 16 + l15) * 32 + q * 8);
#pragma unroll
    for (int j = 0; j < 4; ++j)
      bfr[j] = *(const bf16x8*)(Bs + (wn * 64 + j * 16 + l15) * 32 + q * 8);
#pragma unroll
    for (int i = 0; i < 4; ++i)
#pragma unroll
      for (int j = 0; j < 4; ++j)
        acc[i][j] = __builtin_amdgcn_mfma_f32_16x16x32_bf16(af[i], bfr[j], acc[i][j], 0, 0, 0);
  }
#pragma unroll
  for (int j = 0; j < 4; ++j) {
    int n = bn * 128 + wn * 64 + j * 16 + l15;
    float bias = (n < 2048) ? Wb[n] : Ub[n - 2048];
#pragma unroll
    for (int i = 0; i < 4; ++i) {
#pragma unroll
      for (int r = 0; r < 4; ++r) {
        int m = bm * 128 + wm * 64 + i * 16 + q * 4 + r;
        xproj[(size_t)m * NP + n] = f2b(acc[i][j][r] + bias);
      }
    }
  }
}

// ------------------------------ grid barrier -------------------------------
__device__ __forceinline__ void gbar(unsigned* bar, unsigned target) {
  __syncthreads();                     // all waves drain vmem (compiler waits before s_barrier)
  if (threadIdx.x == 0) {
    __threadfence();                   // release: flush dirty L2 to LLC (cross-XCD)
    __hip_atomic_fetch_add(bar, 1u, __ATOMIC_RELAXED, __HIP_MEMORY_SCOPE_AGENT);
    while (__hip_atomic_fetch_add(bar, 0u, __ATOMIC_RELAXED, __HIP_MEMORY_SCOPE_AGENT) < target)
      __builtin_amdgcn_s_sleep(4);
    __threadfence();                   // acquire: invalidate stale L2/L1
  }
  __syncthreads();
}

// ------------------------------ sequential scan ----------------------------
// 64 blocks x 256 thr (4 waves). gw = global wave 0..255.
// Phase A: a_nt = gw>>1 (16 gi-cols), a_mh = gw&1 (32 batch rows), K=1024.
// Phase B: b_nt = gw>>2 (16 c-cols), b_mh = (gw>>1)&1, b_kh = gw&1 (K halves).
__global__ void __launch_bounds__(256, 1)
k_seq(const u16* __restrict__ xproj, const u16* __restrict__ Wht,
      const u16* __restrict__ Uht, float* __restrict__ h_fp,
      u16* __restrict__ h_bf, u16* __restrict__ rh, float* __restrict__ u_fp,
      float* __restrict__ out, unsigned* __restrict__ bar) {
  __shared__ f32x4 red[2][2][64];
  const int tid = threadIdx.x;
  const int lane = tid & 63;
  const int w = tid >> 6;
  const int gw = blockIdx.x * 4 + w;
  const int l15 = lane & 15;
  const int q = lane >> 4;

  const int a_nt = gw >> 1;
  const int a_mh = gw & 1;
  const int b_nt = gw >> 2;
  const int b_mh = (gw >> 1) & 1;
  const int b_kh = gw & 1;
  const int a_col = a_nt * 16 + l15;        // gi column 0..2047
  const int b_col = b_nt * 16 + l15;        // c column 0..1023

  // ---- recurrent weights -> registers (live for the whole scan) ----
  bf16x8 wa[32];
  {
    const u16* p = Wht + (size_t)a_col * 1024 + q * 8;
#pragma unroll
    for (int s = 0; s < 32; ++s) wa[s] = *(const bf16x8*)(p + s * 32);
  }
  bf16x8 wb[16];
  {
    const u16* p = Uht + (size_t)b_col * 1024 + b_kh * 512 + q * 8;
#pragma unroll
    for (int s = 0; s < 16; ++s) wb[s] = *(const bf16x8*)(p + s * 32);
  }

  // prefetch gx for t=0
  float gxp[2][4];
#pragma unroll
  for (int i = 0; i < 2; ++i)
#pragma unroll
    for (int r = 0; r < 4; ++r) {
      int mb = a_mh * 32 + i * 16 + q * 4 + r;
      gxp[i][r] = b2f(xproj[(size_t)(mb * Tt + 0) * NP + a_col]);
    }

  unsigned tgt = 0;
#pragma unroll 1
  for (int t = 0; t < Tt; ++t) {
    // ============================ Phase A ============================
    float hfp_s[2][4];
    if (a_nt < 64) {
#pragma unroll
      for (int i = 0; i < 2; ++i)
#pragma unroll
        for (int r = 0; r < 4; ++r) {
          int mb = a_mh * 32 + i * 16 + q * 4 + r;
          hfp_s[i][r] = h_fp[mb * 1024 + a_col];
        }
    }
    f32x4 acc0 = {0.f, 0.f, 0.f, 0.f}, acc1 = {0.f, 0.f, 0.f, 0.f};
    {
      const u16* hb0 = h_bf + (size_t)(a_mh * 32 + l15) * 1024 + q * 8;
      const u16* hb1 = hb0 + 16 * 1024;
#pragma unroll
      for (int s = 0; s < 32; ++s) {
        bf16x8 a0 = *(const bf16x8*)(hb0 + s * 32);
        bf16x8 a1 = *(const bf16x8*)(hb1 + s * 32);
        acc0 = __builtin_amdgcn_mfma_f32_16x16x32_bf16(a0, wa[s], acc0, 0, 0, 0);
        acc1 = __builtin_amdgcn_mfma_f32_16x16x32_bf16(a1, wa[s], acc1, 0, 0, 0);
      }
    }
    if (a_nt < 64) {  // r-columns -> rh (bf16)
#pragma unroll
      for (int i = 0; i < 2; ++i) {
        f32x4 a = i ? acc1 : acc0;
#pragma unroll
        for (int r = 0; r < 4; ++r) {
          int mb = a_mh * 32 + i * 16 + q * 4 + r;
          float g = sigmoidf_(a[r] + gxp[i][r]);
          rh[mb * 1024 + a_col] = f2b(g * hfp_s[i][r]);
        }
      }
    } else {          // u-columns -> u_fp (fp32)
#pragma unroll
      for (int i = 0; i < 2; ++i) {
        f32x4 a = i ? acc1 : acc0;
#pragma unroll
        for (int r = 0; r < 4; ++r) {
          int mb = a_mh * 32 + i * 16 + q * 4 + r;
          u_fp[mb * 1024 + (a_col - 1024)] = sigmoidf_(a[r] + gxp[i][r]);
        }
      }
    }
    tgt += GSEQ; gbar(bar, tgt);

    // ============================ Phase B ============================
    if (t + 1 < Tt) {  // prefetch next step's gx (static data, long latency)
#pragma unroll
      for (int i = 0; i < 2; ++i)
#pragma unroll
        for (int r = 0; r < 4; ++r) {
          int mb = a_mh * 32 + i * 16 + q * 4 + r;
          gxp[i][r] = b2f(xproj[(size_t)(mb * Tt + (t + 1)) * NP + a_col]);
        }
    }
    float uxp[2][4], up[2][4], hp[2][4];
    if (b_kh == 0) {
#pragma unroll
      for (int i = 0; i < 2; ++i)
#pragma unroll
        for (int r = 0; r < 4; ++r) {
          int mb = b_mh * 32 + i * 16 + q * 4 + r;
          uxp[i][r] = b2f(xproj[(size_t)(mb * Tt + t) * NP + 2048 + b_col]);
          up[i][r] = u_fp[mb * 1024 + b_col];
          hp[i][r] = h_fp[mb * 1024 + b_col];
        }
    }
    f32x4 bc0 = {0.f, 0.f, 0.f, 0.f}, bc1 = {0.f, 0.f, 0.f, 0.f};
    {
      const u16* rb0 = rh + (size_t)(b_mh * 32 + l15) * 1024 + b_kh * 512 + q * 8;
      const u16* rb1 = rb0 + 16 * 1024;
#pragma unroll
      for (int s = 0; s < 16; ++s) {
        bf16x8 a0 = *(const bf16x8*)(rb0 + s * 32);
        bf16x8 a1 = *(const bf16x8*)(rb1 + s * 32);
        bc0 = __builtin_amdgcn_mfma_f32_16x16x32_bf16(a0, wb[s], bc0, 0, 0, 0);
        bc1 = __builtin_amdgcn_mfma_f32_16x16x32_bf16(a1, wb[s], bc1, 0, 0, 0);
      }
    }
    if (b_kh == 1) { red[w >> 1][0][lane] = bc0; red[w >> 1][1][lane] = bc1; }
    __syncthreads();
    if (b_kh == 0) {
      bc0 += red[w >> 1][0][lane];
      bc1 += red[w >> 1][1][lane];
#pragma unroll
      for (int i = 0; i < 2; ++i) {
        f32x4 a = i ? bc1 : bc0;
#pragma unroll
        for (int r = 0; r < 4; ++r) {
          int mb = b_mh * 32 + i * 16 + q * 4 + r;
          float c = tanhf_(a[r] + uxp[i][r]);
          float u = up[i][r];
          float hn = u * hp[i][r] + (1.0f - u) * c;
          h_fp[mb * 1024 + b_col] = hn;
          h_bf[mb * 1024 + b_col] = f2b(hn);
          out[((size_t)mb * Tt + t) * 1024 + b_col] = hn;
        }
      }
    }
    tgt += GSEQ; gbar(bar, tgt);
  }
}

// --------------------------------- launch ----------------------------------
extern "C" void kernel_launch(void* const* d_in, const int* in_sizes, int n_in,
                              void* d_out, int out_size, void* d_ws, size_t ws_size,
                              hipStream_t stream) {
  const float* x  = (const float*)d_in[0];
  const float* h0 = (const float*)d_in[1];
  const float* W  = (const float*)d_in[2];
  const float* Wb = (const float*)d_in[3];
  const float* U  = (const float*)d_in[4];
  const float* Ub = (const float*)d_in[5];
  float* out = (float*)d_out;

  if (ws_size < WS_NEEDED) {  // sentinel path: absmax ~12345 tells us ws is too small
    k_ws_too_small<<<1, 256, 0, stream>>>(out);
    return;
  }

  char* ws = (char*)d_ws;
  u16* xproj = (u16*)(ws + OFF_XPROJ);
  u16* xbf   = (u16*)(ws + OFF_XBF);
  u16* Pt    = (u16*)(ws + OFF_PT);
  u16* Wht   = (u16*)(ws + OFF_WHT);
  u16* Uht   = (u16*)(ws + OFF_UHT);
  float* h_fp = (float*)(ws + OFF_HFP);
  u16* h_bf   = (u16*)(ws + OFF_HBF);
  u16* rhb    = (u16*)(ws + OFF_RH);
  float* u_fp = (float*)(ws + OFF_UFP);
  unsigned* bar = (unsigned*)(ws + OFF_BAR);

  k_prep_x<<<2048, 256, 0, stream>>>(x, xbf, h0, h_fp, h_bf, bar);
  k_prep_w<<<768, 256, 0, stream>>>(W, U, Pt, Wht, Uht);
  k_gemm<<<dim3(256, 24), 256, 0, stream>>>(xbf, Pt, Wb, Ub, xproj);
  k_seq<<<GSEQ, 256, 0, stream>>>(xproj, Wht, Uht, h_fp, h_bf, rhb, u_fp, out, bar);
}

// Round 2
// 9624.351 us; speedup vs baseline: 1.4387x; 1.4387x over previous
//
#include <hip/hip_runtime.h>
#include <hip/hip_bf16.h>
#include <stdint.h>

// ---------------------------------------------------------------------------
// GRU over sequence. B=64, T=512, D=1024, H=1024.
//   Precompute: xproj[m][0:2048]   = x@W[:D] + W_b   (m = b*T + t)
//               xproj[m][2048:3072]= x@U[:D] + U_b
//   Sequential: persistent 64 blocks x 512 thr, 2 grid barriers/step.
//     Block owns batch-row group mh = b&3 (16 rows). h fp32 carry lives in
//     registers (same wave owns same (row,col) forever). Cross-block data
//     (h_bf, rh, u) moves via agent-scope relaxed atomics (sc1 -> LLC), so
//     NO cache-flush fences are needed. Barrier: fetch_add arrive +
//     LOAD-poll (round-1's RMW-poll serialized at ~13us/barrier).
// ---------------------------------------------------------------------------

typedef unsigned short u16;
typedef unsigned long long u64;
typedef __attribute__((ext_vector_type(8))) short bf16x8;
typedef __attribute__((ext_vector_type(4))) float f32x4;

constexpr int Bsz = 64, Tt = 512, Dd = 1024, Hh = 1024;
constexpr int Mrows = Bsz * Tt;   // 32768
constexpr int NP = 3 * Hh;        // 3072
constexpr int NBLK = 64, THR = 512;

// workspace layout (bytes)
constexpr size_t SZ_XPROJ = (size_t)Mrows * NP * 2;   // 201326592
constexpr size_t SZ_XBF   = (size_t)Mrows * Dd * 2;   //  67108864
constexpr size_t SZ_PT    = (size_t)NP * 1024 * 2;    //   6291456
constexpr size_t SZ_WHT   = (size_t)2048 * 1024 * 2;  //   4194304
constexpr size_t SZ_UHT   = (size_t)1024 * 1024 * 2;  //   2097152
constexpr size_t OFF_XPROJ = 0;
constexpr size_t OFF_XBF   = OFF_XPROJ + SZ_XPROJ;
constexpr size_t OFF_PT    = OFF_XBF + SZ_XBF;
constexpr size_t OFF_WHT   = OFF_PT + SZ_PT;
constexpr size_t OFF_UHT   = OFF_WHT + SZ_WHT;
constexpr size_t OFF_HG    = OFF_UHT + SZ_UHT;          // h:  [4][1024][16] u16 = 128KB
constexpr size_t OFF_RHG   = OFF_HG  + 131072;          // rh: [4][1024][16] u16 = 128KB
constexpr size_t OFF_UFP   = OFF_RHG + 131072;          // u:  [64][1024] f32 = 256KB
constexpr size_t OFF_BAR   = OFF_UFP + 262144;          // 64B
constexpr size_t WS_NEEDED = OFF_BAR + 64;

__device__ __forceinline__ float b2f(u16 u) {
  union { unsigned i; float f; } x; x.i = ((unsigned)u) << 16; return x.f;
}
__device__ __forceinline__ u16 f2b(float f) {
  union { float f; unsigned i; } x; x.f = f;
  unsigned r = (x.i >> 16) & 1u;
  return (u16)((x.i + 0x7fffu + r) >> 16);
}
__device__ __forceinline__ float sigmoidf_(float x) { return 1.0f / (1.0f + __expf(-x)); }
__device__ __forceinline__ float tanhf_(float x) { return 1.0f - 2.0f / (__expf(2.0f * x) + 1.0f); }

__device__ __forceinline__ u64 ldA_u64(const u64* p) {
  return __hip_atomic_load(p, __ATOMIC_RELAXED, __HIP_MEMORY_SCOPE_AGENT);
}
__device__ __forceinline__ void stA_u64(u64* p, u64 v) {
  __hip_atomic_store(p, v, __ATOMIC_RELAXED, __HIP_MEMORY_SCOPE_AGENT);
}
__device__ __forceinline__ float ldA_f32(const float* p) {
  return __hip_atomic_load(p, __ATOMIC_RELAXED, __HIP_MEMORY_SCOPE_AGENT);
}
__device__ __forceinline__ void stA_f32(float* p, float v) {
  __hip_atomic_store(p, v, __ATOMIC_RELAXED, __HIP_MEMORY_SCOPE_AGENT);
}

// async global->LDS, 16B per lane (used by k_gemm only)
__device__ __forceinline__ void gl2lds16(const void* g, void* l) {
  __builtin_amdgcn_global_load_lds(
      (const __attribute__((address_space(1))) void*)g,
      (__attribute__((address_space(3))) void*)l, 16, 0, 0);
}

// ------------------------------- prep kernels ------------------------------
__global__ void k_prep_x(const float* __restrict__ x, u16* __restrict__ xbf,
                         const float* __restrict__ h0, u16* __restrict__ h_g,
                         unsigned* __restrict__ bar) {
  size_t i = (size_t)blockIdx.x * blockDim.x + threadIdx.x;
  size_t stride = (size_t)gridDim.x * blockDim.x;
  if (i < 16) bar[i] = 0u;
  for (size_t k = i; k < (size_t)Mrows * Dd; k += stride) xbf[k] = f2b(x[k]);
  // h_g[g][c][r] = f2b(h0[(g*16+r)*1024 + c])
  for (size_t k = i; k < (size_t)Bsz * Hh; k += stride) {
    int r = (int)(k & 15), c = (int)((k >> 4) & 1023), g = (int)(k >> 14);
    h_g[k] = f2b(h0[(size_t)(g * 16 + r) * 1024 + c]);
  }
}

// coalesced reads: grid (24, 1024), block 256. blockIdx.y = k.
__global__ void k_prep_w(const float* __restrict__ W, const float* __restrict__ U,
                         u16* __restrict__ Pt, u16* __restrict__ Wht, u16* __restrict__ Uht) {
  int k = blockIdx.y, xb = blockIdx.x, tid = threadIdx.x;
  if (xb < 12) {            // Pt[n][k], n 0..3071
    int n = xb * 256 + tid;
    float v = (n < 2048) ? W[(size_t)k * 2048 + n] : U[(size_t)k * 1024 + (n - 2048)];
    Pt[(size_t)n * 1024 + k] = f2b(v);
  } else if (xb < 20) {     // Wht[n][k] = W[1024+k][n], n 0..2047
    int n = (xb - 12) * 256 + tid;
    Wht[(size_t)n * 1024 + k] = f2b(W[(size_t)(1024 + k) * 2048 + n]);
  } else {                  // Uht[n][k] = U[1024+k][n], n 0..1023
    int n = (xb - 20) * 256 + tid;
    Uht[(size_t)n * 1024 + k] = f2b(U[(size_t)(1024 + k) * 1024 + n]);
  }
}

__global__ void k_ws_too_small(float* out) {
  out[threadIdx.x] = 12345.0f;  // sentinel: ws_size < WS_NEEDED
}

// --------------------------- precompute GEMM (m97) -------------------------
__global__ void k_gemm(const u16* __restrict__ xbf, const u16* __restrict__ Pt,
                       const float* __restrict__ Wb, const float* __restrict__ Ub,
                       u16* __restrict__ xproj) {
  __shared__ u16 As[128 * 32];
  __shared__ u16 Bs[128 * 32];
  const int tid = threadIdx.x, lane = tid & 63, w = tid >> 6;
  const int l15 = lane & 15, q = lane >> 4;
  const int bm = blockIdx.x, bn = blockIdx.y;
  const int wm = w >> 1, wn = w & 1;
  const int lr = lane >> 2;
  const int lc = (lane & 3) * 8;
  f32x4 acc[4][4] = {};
  for (int kt = 0; kt < 32; ++kt) {
    __syncthreads();
    {
      const u16* ga = xbf + (size_t)(bm * 128 + w * 32 + lr) * 1024 + kt * 32 + lc;
      gl2lds16(ga, As + w * 1024);
      gl2lds16(ga + 16 * 1024, As + w * 1024 + 512);
      const u16* gb = Pt + (size_t)(bn * 128 + w * 32 + lr) * 1024 + kt * 32 + lc;
      gl2lds16(gb, Bs + w * 1024);
      gl2lds16(gb + 16 * 1024, Bs + w * 1024 + 512);
    }
    __syncthreads();
    bf16x8 af[4], bfr[4];
#pragma unroll
    for (int i = 0; i < 4; ++i)
      af[i] = *(const bf16x8*)(As + (wm * 64 + i * 16 + l15) * 32 + q * 8);
#pragma unroll
    for (int j = 0; j < 4; ++j)
      bfr[j] = *(const bf16x8*)(Bs + (wn * 64 + j * 16 + l15) * 32 + q * 8);
#pragma unroll
    for (int i = 0; i < 4; ++i)
#pragma unroll
      for (int j = 0; j < 4; ++j)
        acc[i][j] = __builtin_amdgcn_mfma_f32_16x16x32_bf16(af[i], bfr[j], acc[i][j], 0, 0, 0);
  }
#pragma unroll
  for (int j = 0; j < 4; ++j) {
    int n = bn * 128 + wn * 64 + j * 16 + l15;
    float bias = (n < 2048) ? Wb[n] : Ub[n - 2048];
#pragma unroll
    for (int i = 0; i < 4; ++i) {
#pragma unroll
      for (int r = 0; r < 4; ++r) {
        int m = bm * 128 + wm * 64 + i * 16 + q * 4 + r;
        xproj[(size_t)m * NP + n] = f2b(acc[i][j][r] + bias);
      }
    }
  }
}

// ------------------------------ grid barrier -------------------------------
// Arrive: one relaxed fetch_add. Poll: relaxed atomic LOAD (no RMW!) +
// s_sleep backoff. Ordering: __syncthreads drains each wave's vmcnt before
// s_barrier; sc1 data stores are already at LLC when the add lands.
__device__ __forceinline__ void gbar(unsigned* bar, unsigned target) {
  __syncthreads();
  if (threadIdx.x == 0) {
    __hip_atomic_fetch_add(bar, 1u, __ATOMIC_RELAXED, __HIP_MEMORY_SCOPE_AGENT);
    while (__hip_atomic_load(bar, __ATOMIC_RELAXED, __HIP_MEMORY_SCOPE_AGENT) < target)
      __builtin_amdgcn_s_sleep(1);
  }
  __syncthreads();
}

// ------------------------------ sequential scan ----------------------------
// 64 blocks x 512 thr (8 waves). Block owns 16 batch rows (mh = b&3).
// Phase A: wave w -> gi col-tile a_nt=(b>>2)*8+w (0..127), 1 MFMA chain, K=1024.
// Phase B: wave pair -> c col-tile b_nt=(b>>2)*4+(w>>1) (0..63), K split by w&1.
__global__ void __launch_bounds__(THR, 2)
k_seq(const u16* __restrict__ xproj, const u16* __restrict__ Wht,
      const u16* __restrict__ Uht, const float* __restrict__ h0,
      u16* __restrict__ h_g, u16* __restrict__ rh_g, float* __restrict__ u_fp,
      float* __restrict__ out, unsigned* __restrict__ bar) {
  __shared__ u16 hs[16 * 1032];      // staged h or rh, row-major, pad 8
  __shared__ f32x4 red[4][64];       // phase-B split-K reduction
  const int tid = threadIdx.x, lane = tid & 63, w = tid >> 6;
  const int l15 = lane & 15, q = lane >> 4;
  const int b = blockIdx.x;
  const int mh = b & 3;              // 16-row batch group
  const int rbase = mh * 16;
  const int a_nt = (b >> 2) * 8 + w;         // 0..127
  const int a_col = a_nt * 16 + l15;         // 0..2047
  const int b_nt = (b >> 2) * 4 + (w >> 1);  // 0..63
  const int b_kh = w & 1;
  const int b_col = b_nt * 16 + l15;         // 0..1023

  // ---- recurrent weights -> registers for the whole scan ----
  bf16x8 wa[32];
  { const u16* p = Wht + (size_t)a_col * 1024 + q * 8;
#pragma unroll
    for (int s = 0; s < 32; ++s) wa[s] = *(const bf16x8*)(p + s * 32); }
  bf16x8 wb[16];
  { const u16* p = Uht + (size_t)b_col * 1024 + b_kh * 512 + q * 8;
#pragma unroll
    for (int s = 0; s < 16; ++s) wb[s] = *(const bf16x8*)(p + s * 32); }

  // fp32 hidden-state carry: wave with b_kh==0 owns rows rbase+q*4+r, col b_col
  float hp[4];
#pragma unroll
  for (int r = 0; r < 4; ++r) hp[r] = h0[(size_t)(rbase + q * 4 + r) * 1024 + b_col];

  // prefetch gx for t=0
  float gxp[4];
#pragma unroll
  for (int r = 0; r < 4; ++r)
    gxp[r] = b2f(xproj[(size_t)((rbase + q * 4 + r) * Tt + 0) * NP + a_col]);

  const u64* hg64 = (const u64*)h_g + mh * 4096;    // [1024 col][4 u64]
  const u64* rg64 = (const u64*)rh_g + mh * 4096;

  unsigned tgt = 0;
#pragma unroll 1
  for (int t = 0; t < Tt; ++t) {
    // ---- stage h (group mh) into LDS: 32KB contiguous, sc1 loads ----
#pragma unroll
    for (int j = 0; j < 8; ++j) {
      int f = j * THR + tid;               // 0..4095
      u64 v = ldA_u64(hg64 + f);
      int col = f >> 2, rr = f & 3;        // rows rr*4..+3
      u16* d = hs + rr * 4 * 1032 + col;
      d[0] = (u16)v; d[1032] = (u16)(v >> 16);
      d[2064] = (u16)(v >> 32); d[3096] = (u16)(v >> 48);
    }
    __syncthreads();

    // ---- phase A: gi tile = h @ Wh[:,a_col tile], K=1024 ----
    f32x4 acc = {0.f, 0.f, 0.f, 0.f};
    {
      const u16* hb = hs + l15 * 1032 + q * 8;
#pragma unroll
      for (int s = 0; s < 32; ++s) {
        bf16x8 a = *(const bf16x8*)(hb + s * 32);
        acc = __builtin_amdgcn_mfma_f32_16x16x32_bf16(a, wa[s], acc, 0, 0, 0);
      }
    }
    if (a_nt < 64) {   // r-columns: rh = sigmoid(gi)*h  (bf16, packed u64)
      u64 pk = 0;
#pragma unroll
      for (int r = 0; r < 4; ++r) {
        int lrow = q * 4 + r;
        float g = sigmoidf_(acc[r] + gxp[r]);
        float hcell = b2f(hs[lrow * 1032 + a_col]);
        pk |= (u64)f2b(g * hcell) << (16 * r);
      }
      stA_u64((u64*)rh_g + mh * 4096 + a_col * 4 + q, pk);
    } else {           // u-columns: fp32
#pragma unroll
      for (int r = 0; r < 4; ++r) {
        int lrow = q * 4 + r;
        stA_f32(&u_fp[(size_t)(rbase + lrow) * 1024 + (a_col - 1024)],
                sigmoidf_(acc[r] + gxp[r]));
      }
    }
    tgt += NBLK; gbar(bar, tgt);

    // ---- stage rh (group mh) into LDS ----
#pragma unroll
    for (int j = 0; j < 8; ++j) {
      int f = j * THR + tid;
      u64 v = ldA_u64(rg64 + f);
      int col = f >> 2, rr = f & 3;
      u16* d = hs + rr * 4 * 1032 + col;
      d[0] = (u16)v; d[1032] = (u16)(v >> 16);
      d[2064] = (u16)(v >> 32); d[3096] = (u16)(v >> 48);
    }
    __syncthreads();

    // ---- phase B: c tile = rh @ Uh[:,b_col tile], K split 2 ----
    f32x4 accb = {0.f, 0.f, 0.f, 0.f};
    {
      const u16* rb = hs + l15 * 1032 + b_kh * 512 + q * 8;
#pragma unroll
      for (int s = 0; s < 16; ++s) {
        bf16x8 a = *(const bf16x8*)(rb + s * 32);
        accb = __builtin_amdgcn_mfma_f32_16x16x32_bf16(a, wb[s], accb, 0, 0, 0);
      }
    }
    if (b_kh == 1) red[w >> 1][lane] = accb;
    __syncthreads();
    if (b_kh == 0) {
      accb += red[w >> 1][lane];
      u64 pk = 0;
#pragma unroll
      for (int r = 0; r < 4; ++r) {
        int grow = rbase + q * 4 + r;
        float ux = b2f(xproj[(size_t)(grow * Tt + t) * NP + 2048 + b_col]);
        float u = ldA_f32(&u_fp[(size_t)grow * 1024 + b_col]);
        float c = tanhf_(accb[r] + ux);
        float hn = u * hp[r] + (1.0f - u) * c;
        hp[r] = hn;
        pk |= (u64)f2b(hn) << (16 * r);
        out[((size_t)grow * Tt + t) * 1024 + b_col] = hn;
      }
      stA_u64((u64*)h_g + mh * 4096 + b_col * 4 + q, pk);
    }
    if (t + 1 < Tt) {  // prefetch next gx (read-only, plain cached)
#pragma unroll
      for (int r = 0; r < 4; ++r)
        gxp[r] = b2f(xproj[(size_t)((rbase + q * 4 + r) * Tt + (t + 1)) * NP + a_col]);
    }
    tgt += NBLK; gbar(bar, tgt);
  }
}

// --------------------------------- launch ----------------------------------
extern "C" void kernel_launch(void* const* d_in, const int* in_sizes, int n_in,
                              void* d_out, int out_size, void* d_ws, size_t ws_size,
                              hipStream_t stream) {
  const float* x  = (const float*)d_in[0];
  const float* h0 = (const float*)d_in[1];
  const float* W  = (const float*)d_in[2];
  const float* Wb = (const float*)d_in[3];
  const float* U  = (const float*)d_in[4];
  const float* Ub = (const float*)d_in[5];
  float* out = (float*)d_out;

  if (ws_size < WS_NEEDED) {
    k_ws_too_small<<<1, 256, 0, stream>>>(out);
    return;
  }

  char* ws = (char*)d_ws;
  u16* xproj = (u16*)(ws + OFF_XPROJ);
  u16* xbf   = (u16*)(ws + OFF_XBF);
  u16* Pt    = (u16*)(ws + OFF_PT);
  u16* Wht   = (u16*)(ws + OFF_WHT);
  u16* Uht   = (u16*)(ws + OFF_UHT);
  u16* h_g   = (u16*)(ws + OFF_HG);
  u16* rh_g  = (u16*)(ws + OFF_RHG);
  float* u_fp = (float*)(ws + OFF_UFP);
  unsigned* bar = (unsigned*)(ws + OFF_BAR);

  k_prep_x<<<2048, 256, 0, stream>>>(x, xbf, h0, h_g, bar);
  k_prep_w<<<dim3(24, 1024), 256, 0, stream>>>(W, U, Pt, Wht, Uht);
  k_gemm<<<dim3(256, 24), 256, 0, stream>>>(xbf, Pt, Wb, Ub, xproj);
  k_seq<<<NBLK, 512, 0, stream>>>(xproj, Wht, Uht, h0, h_g, rh_g, u_fp, out, bar);
}